// Round 3
// baseline (669.197 us; speedup 1.0000x reference)
//
#include <hip/hip_runtime.h>
#include <math.h>

// CosFace-style loss:
//   num_i   = S*(x[i,y_i] - M)
//   sum_i   = sum_j exp(S*x[i,j])
//   denom_i = exp(num_i) + (sum_i - exp(S*x[i,y_i]))
//   L_i     = (num_i - log(denom_i)) / S
//   out     = -mean_i(L_i)
// Memory-bound: 409.6 MB read of x, roofline ~65 us @ 6.3 TB/s.
// R3: INSTRUMENTATION ROUND. Accounting from R2 counters: dur(499) = one ws
// poison fill (253) + our kernels (~246 => ~1.67 TB/s read, 26% of peak).
// Added probe_read_kernel: pure float4 grid-stride read of x, TWICE (819 MB),
// fp32 adds only, asm keep-alive. If the probe also runs ~1.7 TB/s, the read
// path/buffer is the problem (H1); if it runs >5 TB/s, our compute loop is
// (H2). Probe is temporary and will be removed next round.

#define SCALE 64.0f
#define MARGIN 0.35f
#define NT 256     // threads per block in partial-sum kernel (4 waves)
#define GSPLIT 4   // blocks per row

typedef float v4f __attribute__((ext_vector_type(4)));

template <int NWAVES>
__device__ __forceinline__ double block_reduce_d(double v) {
    #pragma unroll
    for (int off = 32; off > 0; off >>= 1) v += __shfl_down(v, off, 64);
    __shared__ double s[NWAVES];
    const int lane = threadIdx.x & 63;
    const int w    = threadIdx.x >> 6;
    if (lane == 0) s[w] = v;
    __syncthreads();
    if (w == 0) {
        v = (lane < NWAVES) ? s[lane] : 0.0;
        #pragma unroll
        for (int off = NWAVES / 2; off > 0; off >>= 1) v += __shfl_down(v, off, 64);
    }
    return v;  // valid in thread 0
}

// Each block computes sum_j exp(S*x[row, j]) over one 1/GSPLIT chunk of a row.
__global__ __launch_bounds__(NT) void partial_sum_kernel(
    const float* __restrict__ x, double* __restrict__ partials, int C)
{
    const int g   = blockIdx.x;   // chunk within row
    const int row = blockIdx.y;
    const float* __restrict__ xr = x + (size_t)row * (size_t)C;
    const int tid = threadIdx.x;

    const int n4    = C >> 2;
    const int begin = (int)(((long long)n4 * g) / GSPLIT);
    const int end   = (int)(((long long)n4 * (g + 1)) / GSPLIT);
    const v4f* __restrict__ x4 = (const v4f*)xr;

    double acc = 0.0;
    int v = begin + tid;
    // 4 independent float4 loads in flight per thread
    for (; v + 3 * NT < end; v += 4 * NT) {
        v4f a = x4[v];
        v4f b = x4[v + NT];
        v4f c = x4[v + 2 * NT];
        v4f d = x4[v + 3 * NT];
        float s0 = __expf(SCALE * a.x) + __expf(SCALE * a.y) +
                   __expf(SCALE * a.z) + __expf(SCALE * a.w);
        float s1 = __expf(SCALE * b.x) + __expf(SCALE * b.y) +
                   __expf(SCALE * b.z) + __expf(SCALE * b.w);
        float s2 = __expf(SCALE * c.x) + __expf(SCALE * c.y) +
                   __expf(SCALE * c.z) + __expf(SCALE * c.w);
        float s3 = __expf(SCALE * d.x) + __expf(SCALE * d.y) +
                   __expf(SCALE * d.z) + __expf(SCALE * d.w);
        acc += (double)(s0 + s1) + (double)(s2 + s3);
    }
    for (; v < end; v += NT) {
        v4f a = x4[v];
        acc += (double)(__expf(SCALE * a.x) + __expf(SCALE * a.y) +
                        __expf(SCALE * a.z) + __expf(SCALE * a.w));
    }
    // scalar tail if C % 4 != 0 (handled by last chunk only)
    if (g == GSPLIT - 1) {
        for (int j = (n4 << 2) + tid; j < C; j += NT)
            acc += (double)__expf(SCALE * xr[j]);
    }

    double s = block_reduce_d<NT / 64>(acc);
    if (tid == 0) partials[(size_t)row * GSPLIT + g] = s;
}

// One block: combine per-row partials, apply margin epilogue, reduce mean.
__global__ __launch_bounds__(1024) void finalize_kernel(
    const float* __restrict__ x, const int* __restrict__ label,
    const double* __restrict__ partials, float* __restrict__ out, int B, int C)
{
    double acc = 0.0;
    for (int row = threadIdx.x; row < B; row += 1024) {
        double rs = 0.0;
        #pragma unroll
        for (int g = 0; g < GSPLIT; ++g) rs += partials[(size_t)row * GSPLIT + g];
        const double xy  = (double)x[(size_t)row * (size_t)C + label[row]];
        const double num = 64.0 * (xy - 0.35);
        const double exy = exp(64.0 * xy);
        const double sum_excl = rs - exy;          // fp64: cancellation-safe
        const double denom = exp(num) + sum_excl;
        acc += (num - log(denom)) / 64.0;
    }
    double total = block_reduce_d<16>(acc);
    if (threadIdx.x == 0) out[0] = (float)(-total / (double)B);
}

// TEMPORARY PROBE: pure float4 read of the whole x buffer, TWICE (819 MB).
// No exp, no fp64, no stores. asm volatile keeps the loads alive (rule #17).
// Measures the raw achievable read BW on THIS buffer with a copy-style loop.
__global__ __launch_bounds__(256) void probe_read_kernel(
    const float* __restrict__ x, int n4)
{
    const v4f* __restrict__ x4 = (const v4f*)x;
    const int nthreads = gridDim.x * blockDim.x;
    const int i0 = blockIdx.x * blockDim.x + threadIdx.x;
    float acc = 0.0f;
    #pragma unroll 1
    for (int p = 0; p < 2; ++p) {
        int v = i0;
        for (; v + 3 * nthreads < n4; v += 4 * nthreads) {
            v4f a = x4[v];
            v4f b = x4[v + nthreads];
            v4f c = x4[v + 2 * nthreads];
            v4f d = x4[v + 3 * nthreads];
            acc += (a.x + a.y + a.z + a.w) + (b.x + b.y + b.z + b.w) +
                   (c.x + c.y + c.z + c.w) + (d.x + d.y + d.z + d.w);
        }
        for (; v < n4; v += nthreads) {
            v4f a = x4[v];
            acc += a.x + a.y + a.z + a.w;
        }
    }
    asm volatile("" :: "v"(acc));  // keep loads live, no store
}

extern "C" void kernel_launch(void* const* d_in, const int* in_sizes, int n_in,
                              void* d_out, int out_size, void* d_ws, size_t ws_size,
                              hipStream_t stream) {
    const float* x     = (const float*)d_in[0];
    const int*   label = (const int*)d_in[1];
    const int B = in_sizes[1];
    const int C = in_sizes[0] / B;

    double* partials = (double*)d_ws;  // B * GSPLIT doubles = 32 KB scratch

    dim3 grid1(GSPLIT, B);
    partial_sum_kernel<<<grid1, NT, 0, stream>>>(x, partials, C);
    finalize_kernel<<<1, 1024, 0, stream>>>(x, label, partials, (float*)d_out, B, C);

    // temporary instrumentation: raw read-BW probe over x (removed next round)
    const long long total4 = ((long long)B * C) >> 2;
    probe_read_kernel<<<2048, 256, 0, stream>>>(x, (int)total4);
}

// Round 4
// 556.470 us; speedup vs baseline: 1.2026x; 1.2026x over previous
//
#include <hip/hip_runtime.h>
#include <math.h>

// CosFace-style loss:
//   num_i   = S*(x[i,y_i] - M)
//   sum_i   = sum_j exp(S*x[i,j])
//   denom_i = exp(num_i) + (sum_i - exp(S*x[i,y_i]))
//   L_i     = (num_i - log(denom_i)) / S
//   out     = -mean_i(L_i)
// Memory-bound: 409.6 MB read of x, roofline ~65 us @ 6.3 TB/s.
// R4: VISIBILITY ROUND. partial_sum has been stuck at ~246 us (1.7 TB/s,
// 26% of peak) across 4 structural variants, but it always lands JUST under
// the ~248-us poison fills in the top-5 table, so we have never seen its
// counters. R3's pure-read probe did the same traversal at ~4.8 TB/s, so the
// read path is fine -- the cost is in this loop. This round the kernel runs
// its traversal TWICE (pass 2 identical, asm-keepalive, no store) to force it
// to the top of the dispatch table and capture VALUBusy / OccupancyPercent /
// FETCH_SIZE. Decision tree in session notes; pass 2 is removed next round.

#define SCALE 64.0f
#define MARGIN 0.35f
#define NT 256     // threads per block in partial-sum kernel (4 waves)
#define GSPLIT 4   // blocks per row

typedef float v4f __attribute__((ext_vector_type(4)));

template <int NWAVES>
__device__ __forceinline__ double block_reduce_d(double v) {
    #pragma unroll
    for (int off = 32; off > 0; off >>= 1) v += __shfl_down(v, off, 64);
    __shared__ double s[NWAVES];
    const int lane = threadIdx.x & 63;
    const int w    = threadIdx.x >> 6;
    if (lane == 0) s[w] = v;
    __syncthreads();
    if (w == 0) {
        v = (lane < NWAVES) ? s[lane] : 0.0;
        #pragma unroll
        for (int off = NWAVES / 2; off > 0; off >>= 1) v += __shfl_down(v, off, 64);
    }
    return v;  // valid in thread 0
}

// One traversal of this block's chunk: sum_j exp(S*x[chunk j]).
__device__ __forceinline__ double chunk_exp_sum(
    const v4f* __restrict__ x4, const float* __restrict__ xr,
    int begin, int end, int n4, int C, int g, int tid)
{
    double acc = 0.0;
    int v = begin + tid;
    // 4 independent float4 loads in flight per thread
    for (; v + 3 * NT < end; v += 4 * NT) {
        v4f a = x4[v];
        v4f b = x4[v + NT];
        v4f c = x4[v + 2 * NT];
        v4f d = x4[v + 3 * NT];
        float s0 = __expf(SCALE * a.x) + __expf(SCALE * a.y) +
                   __expf(SCALE * a.z) + __expf(SCALE * a.w);
        float s1 = __expf(SCALE * b.x) + __expf(SCALE * b.y) +
                   __expf(SCALE * b.z) + __expf(SCALE * b.w);
        float s2 = __expf(SCALE * c.x) + __expf(SCALE * c.y) +
                   __expf(SCALE * c.z) + __expf(SCALE * c.w);
        float s3 = __expf(SCALE * d.x) + __expf(SCALE * d.y) +
                   __expf(SCALE * d.z) + __expf(SCALE * d.w);
        acc += (double)(s0 + s1) + (double)(s2 + s3);
    }
    for (; v < end; v += NT) {
        v4f a = x4[v];
        acc += (double)(__expf(SCALE * a.x) + __expf(SCALE * a.y) +
                        __expf(SCALE * a.z) + __expf(SCALE * a.w));
    }
    // scalar tail if C % 4 != 0 (handled by last chunk only)
    if (g == GSPLIT - 1) {
        for (int j = (n4 << 2) + tid; j < C; j += NT)
            acc += (double)__expf(SCALE * xr[j]);
    }
    return acc;
}

// Each block computes sum_j exp(S*x[row, j]) over one 1/GSPLIT chunk of a row.
__global__ __launch_bounds__(NT) void partial_sum_kernel(
    const float* __restrict__ x, double* __restrict__ partials, int C)
{
    const int g   = blockIdx.x;   // chunk within row
    const int row = blockIdx.y;
    const float* __restrict__ xr = x + (size_t)row * (size_t)C;
    const int tid = threadIdx.x;

    const int n4    = C >> 2;
    const int begin = (int)(((long long)n4 * g) / GSPLIT);
    const int end   = (int)(((long long)n4 * (g + 1)) / GSPLIT);
    const v4f* __restrict__ x4 = (const v4f*)xr;

    // pass 1: the real computation
    double acc = chunk_exp_sum(x4, xr, begin, end, n4, C, g, tid);

    // pass 2: TEMPORARY instrumentation -- identical work, kept alive but
    // unused, to double this kernel's duration past the ~250-us poison fills
    // so rocprof's top-5 table shows OUR counters. Removed next round.
    double acc2 = chunk_exp_sum(x4, xr, begin, end, n4, C, g, tid);
    asm volatile("" :: "v"(acc2));

    double s = block_reduce_d<NT / 64>(acc);
    if (tid == 0) partials[(size_t)row * GSPLIT + g] = s;
}

// One block: combine per-row partials, apply margin epilogue, reduce mean.
__global__ __launch_bounds__(1024) void finalize_kernel(
    const float* __restrict__ x, const int* __restrict__ label,
    const double* __restrict__ partials, float* __restrict__ out, int B, int C)
{
    double acc = 0.0;
    for (int row = threadIdx.x; row < B; row += 1024) {
        double rs = 0.0;
        #pragma unroll
        for (int g = 0; g < GSPLIT; ++g) rs += partials[(size_t)row * GSPLIT + g];
        const double xy  = (double)x[(size_t)row * (size_t)C + label[row]];
        const double num = 64.0 * (xy - 0.35);
        const double exy = exp(64.0 * xy);
        const double sum_excl = rs - exy;          // fp64: cancellation-safe
        const double denom = exp(num) + sum_excl;
        acc += (num - log(denom)) / 64.0;
    }
    double total = block_reduce_d<16>(acc);
    if (threadIdx.x == 0) out[0] = (float)(-total / (double)B);
}

extern "C" void kernel_launch(void* const* d_in, const int* in_sizes, int n_in,
                              void* d_out, int out_size, void* d_ws, size_t ws_size,
                              hipStream_t stream) {
    const float* x     = (const float*)d_in[0];
    const int*   label = (const int*)d_in[1];
    const int B = in_sizes[1];
    const int C = in_sizes[0] / B;

    double* partials = (double*)d_ws;  // B * GSPLIT doubles = 32 KB scratch

    dim3 grid1(GSPLIT, B);
    partial_sum_kernel<<<grid1, NT, 0, stream>>>(x, partials, C);
    finalize_kernel<<<1, 1024, 0, stream>>>(x, label, partials, (float*)d_out, B, C);
}